// Round 12
// baseline (2534.140 us; speedup 1.0000x reference)
//
#include <hip/hip_runtime.h>
#include <hip/hip_bf16.h>
#include <hip/hip_cooperative_groups.h>
#include <math.h>

namespace cg = cooperative_groups;

#define NN 50000
#define NE 800000
#define NG 256
#define FHH 128
#define NL 6
#define NCH 49    // ceil(50000/1024)
#define NB 391    // ceil(50000/128) row-blocks
#define NTILE (49 * 32)   // gemm tiles: 4 mats x NB, XCD-swizzle-mapped

typedef __attribute__((ext_vector_type(8))) short s16x8;
typedef __attribute__((ext_vector_type(4))) float f32x4;

#define QSCALE 0.36067376022224085f   // 0.25 * log2(e)

__device__ __forceinline__ ushort f2bf(float x) {
  uint u = __float_as_uint(x);
  u += 0x7fffu + ((u >> 16) & 1u);
  return (ushort)(u >> 16);
}
__device__ __forceinline__ float bf2f(ushort h) {
  return __uint_as_float(((uint)h) << 16);
}
__device__ __forceinline__ float bfl(uint u) { return __uint_as_float(u << 16); }
__device__ __forceinline__ float bfh(uint u) { return __uint_as_float(u & 0xffff0000u); }
__device__ __forceinline__ uint packbf(float a, float b) {
  return (uint)f2bf(a) | ((uint)f2bf(b) << 16);
}

__device__ __forceinline__ void gload16(const ushort* g, ushort* l) {
  __builtin_amdgcn_global_load_lds(
      (const __attribute__((address_space(1))) uint*)(const void*)g,
      (__attribute__((address_space(3))) uint*)(void*)l, 16, 0, 0);
}

// ---------------- graph-boundary search (batch_vec sorted) ----------------
__global__ void k_gstart(const int* __restrict__ bv, int* __restrict__ gstart) {
  int g = blockIdx.x * blockDim.x + threadIdx.x;
  if (g > NG) return;
  int lo = 0, hi = NN;
  while (lo < hi) { int mid = (lo + hi) >> 1; if (bv[mid] < g) lo = mid + 1; else hi = mid; }
  gstart[g] = lo;
}

// ---------------- CSR build (by dst) ----------------
__global__ void k_deg(const int* __restrict__ dstv, int* __restrict__ deg) {
  int e = blockIdx.x * blockDim.x + threadIdx.x;
  if (e < NE) atomicAdd(&deg[dstv[e]], 1);
}

__global__ __launch_bounds__(256) void k_scanA(const int* __restrict__ deg, int* __restrict__ part) {
  int b = blockIdx.x, t = threadIdx.x;
  int s = 0;
  for (int j = t; j < 1024; j += 256) { int i = b * 1024 + j; if (i < NN) s += deg[i]; }
  __shared__ int sh[4];
  for (int o = 32; o; o >>= 1) s += __shfl_down(s, o, 64);
  if ((t & 63) == 0) sh[t >> 6] = s;
  __syncthreads();
  if (t == 0) part[b] = sh[0] + sh[1] + sh[2] + sh[3];
}

__global__ void k_scanB(int* __restrict__ part, int* __restrict__ row_ptr) {
  if (threadIdx.x == 0 && blockIdx.x == 0) {
    int run = 0;
    for (int i = 0; i < NCH; ++i) { int v = part[i]; part[i] = run; run += v; }
    row_ptr[NN] = run;
  }
}

__global__ __launch_bounds__(1024) void k_scanC(const int* __restrict__ deg, const int* __restrict__ part,
                                                int* __restrict__ row_ptr, int* __restrict__ cursor) {
  __shared__ int buf[1024];
  int b = blockIdx.x, t = threadIdx.x;
  int i = b * 1024 + t;
  int v = (i < NN) ? deg[i] : 0;
  buf[t] = v;
  __syncthreads();
  for (int off = 1; off < 1024; off <<= 1) {
    int add = (t >= off) ? buf[t - off] : 0;
    __syncthreads();
    buf[t] += add;
    __syncthreads();
  }
  if (i < NN) { int ex = part[b] + buf[t] - v; row_ptr[i] = ex; cursor[i] = ex; }
}

// col stores BYTE offsets of kv rows (src * 512)
__global__ void k_scatter(const int* __restrict__ srcv, const int* __restrict__ dstv,
                          int* __restrict__ cursor, uint* __restrict__ colb) {
  int e = blockIdx.x * blockDim.x + threadIdx.x;
  if (e < NE) {
    int d = dstv[e];
    int pos = atomicAdd(&cursor[d], 1);
    colb[pos] = ((uint)srcv[e]) << 9;
  }
}

// ---------------- weight preconvert: fragment-order tiles ----------------
__device__ __forceinline__ size_t wtile_idx(int k, int c) {
  return (size_t)(k >> 5) * 4096 + ((((c >> 4) * 4 + ((k & 31) >> 3)) * 16 + (c & 15)) * 8 + (k & 7));
}

__global__ __launch_bounds__(256) void k_wconv0(const float* __restrict__ W0, const float* __restrict__ W1,
                                                const float* __restrict__ W2, const float* __restrict__ W3,
                                                ushort* __restrict__ wh, ushort* __restrict__ wl) {
  int id = blockIdx.x * 256 + threadIdx.x;           // 4*64*128 = 32768
  if (id >= 4 * 64 * 128) return;
  int mat = id >> 13, rem = id & 8191;
  int k = rem >> 7, c = rem & 127;
  const float* W = (mat == 0) ? W0 : (mat == 1) ? W1 : (mat == 2) ? W2 : W3;
  float v = W[k * 128 + c];
  ushort h = f2bf(v);
  ushort lo = f2bf(v - bf2f(h));
  size_t dst = (size_t)mat * 8192 + wtile_idx(k, c);
  wh[dst] = h; wl[dst] = lo;
}

__global__ __launch_bounds__(256) void k_wconvS(const float* __restrict__ Wq, const float* __restrict__ Wk,
                                                const float* __restrict__ Wv, const float* __restrict__ Ws,
                                                ushort* __restrict__ wh, ushort* __restrict__ wl) {
  int id = blockIdx.x * 256 + threadIdx.x;           // 5*4*128*128 = 327680
  if (id >= 5 * 4 * 16384) return;
  int lay = id / 65536, rem = id % 65536;
  int mat = rem >> 14, rem2 = rem & 16383;
  int k = rem2 >> 7, c = rem2 & 127;
  const float* W = (mat == 0) ? Wq : (mat == 1) ? Wk : (mat == 2) ? Wv : Ws;
  float v = W[(size_t)lay * 16384 + k * 128 + c];
  ushort h = f2bf(v);
  ushort lo = f2bf(v - bf2f(h));
  size_t dst = 32768 + ((size_t)lay * 4 + mat) * 16384 + wtile_idx(k, c);
  wh[dst] = h; wl[dst] = lo;
}

// ---------------- presplit (layer-0 input only): bf16-high, fragment-order tiled ----------------
template <int K>
__global__ __launch_bounds__(256) void k_presplit(const float* __restrict__ Y,
                                                  ushort* __restrict__ Xh) {
  const int CP = K / 4;
  int idx = blockIdx.x * 256 + threadIdx.x;
  int row = idx / CP;
  int c4 = (idx % CP) * 4;
  if (row >= NN) return;
  float4 v = *reinterpret_cast<const float4*>(Y + (size_t)row * K + c4);
  ushort h0 = f2bf(v.x), h1 = f2bf(v.y), h2 = f2bf(v.z), h3 = f2bf(v.w);
  int b = row >> 7, g = (row & 127) >> 4, frow = row & 15;
  int ks = c4 >> 5, qq = (c4 & 31) >> 3, j = c4 & 7;
  size_t base = ((size_t)ks * NB + b) * 4096 + (((g * 4 + qq) * 16) + frow) * 8 + j;
  *reinterpret_cast<uint2*>(Xh + base) =
      make_uint2((uint)h0 | ((uint)h1 << 16), (uint)h2 | ((uint)h3 << 16));
}

// =================== cooperative mega-kernel: all 6 layers ===================
// Phases per layer: gemm (2-pass split-bf16 MFMA) -> agg -> bnstats -> post.
// grid.sync() between phases. All early-exits are guards (every block syncs).
// LDS: 24 KB union (gemm Ah/Bh/Bl | bnstats s1/s2 | post acts/sg/ssc/ssh).
__global__ __launch_bounds__(256) void k_layers(
    const ushort* __restrict__ wsh, const ushort* __restrict__ wsl,
    const float* __restrict__ bq0, const float* __restrict__ bk0,
    const float* __restrict__ bv0, const float* __restrict__ bs0,
    const float* __restrict__ bqS, const float* __restrict__ bkS,
    const float* __restrict__ bvS, const float* __restrict__ bsS,
    const float* __restrict__ gamma, const float* __restrict__ beta,
    const int* __restrict__ bvec, const int* __restrict__ gstart,
    const int* __restrict__ row_ptr, const uint* __restrict__ colb,
    ushort* __restrict__ qbf, ushort* __restrict__ kv, ushort* __restrict__ xsb,
    uint* __restrict__ yb, ushort* __restrict__ Xh,
    float* __restrict__ bstat, float* __restrict__ out) {
  cg::grid_group grid = cg::this_grid();
  __shared__ __align__(16) char sbuf[24576];
  ushort* Ah = (ushort*)sbuf;
  ushort* Bh = (ushort*)(sbuf + 8192);
  ushort* Bl = (ushort*)(sbuf + 16384);
  const int NBLK = gridDim.x;
  const int t = threadIdx.x;

  for (int l = 0; l < NL; ++l) {
    const int K = (l == 0) ? 64 : 128;
    const int nks = K >> 5;
    const int matstride = K << 7;
    const ushort* WthL = wsh + ((l == 0) ? 0 : (size_t)32768 + (size_t)(l - 1) * 65536);
    const ushort* WtlL = wsl + ((l == 0) ? 0 : (size_t)32768 + (size_t)(l - 1) * 65536);
    const float *bq_, *bk_, *bv_, *bs_;
    if (l == 0) { bq_ = bq0; bk_ = bk0; bv_ = bv0; bs_ = bs0; }
    else {
      size_t bo = (size_t)(l - 1) * FHH;
      bq_ = bqS + bo; bk_ = bkS + bo; bv_ = bvS + bo; bs_ = bsS + bo;
    }
    float* lstat = bstat + (size_t)l * 2 * FHH;

    // ---------- phase 1: GEMM ----------
    {
      int lane = t & 63, w = t >> 6;
      int wr = w >> 1, wc = w & 1;
      int frow = lane & 15;
      int wofs = w * 1024 + lane * 8;
      for (int tile = blockIdx.x; tile < NTILE; tile += NBLK) {
        int mat = (tile >> 3) & 3;
        int b = (tile & 7) + ((tile >> 5) << 3);
        if (b < NB) {
          const ushort* wh = WthL + (size_t)mat * matstride;
          const ushort* wl = WtlL + (size_t)mat * matstride;
          const float* bb = (mat == 0) ? bq_ : (mat == 1) ? bk_ : (mat == 2) ? bv_ : bs_;
          f32x4 acc[4][4];
#pragma unroll
          for (int i = 0; i < 4; ++i)
#pragma unroll
            for (int j = 0; j < 4; ++j)
#pragma unroll
              for (int r = 0; r < 4; ++r) acc[i][j][r] = 0.f;
          for (int ks = 0; ks < nks; ++ks) {
            size_t abase = ((size_t)ks * NB + b) * 4096;
            const ushort* gAh = Xh + abase + wofs;
            const ushort* gBh = wh + ks * 4096 + wofs;
            const ushort* gBl = wl + ks * 4096 + wofs;
            gload16(gAh, &Ah[w * 1024]);
            gload16(gAh + 512, &Ah[w * 1024 + 512]);
            gload16(gBh, &Bh[w * 1024]);
            gload16(gBh + 512, &Bh[w * 1024 + 512]);
            gload16(gBl, &Bl[w * 1024]);
            gload16(gBl + 512, &Bl[w * 1024 + 512]);
            __syncthreads();
            s16x8 ah[4], bh[4], bl[4];
#pragma unroll
            for (int g = 0; g < 4; ++g) {
              ah[g] = *reinterpret_cast<const s16x8*>(&Ah[(wr * 4 + g) * 512 + lane * 8]);
              bh[g] = *reinterpret_cast<const s16x8*>(&Bh[(wc * 4 + g) * 512 + lane * 8]);
              bl[g] = *reinterpret_cast<const s16x8*>(&Bl[(wc * 4 + g) * 512 + lane * 8]);
            }
#pragma unroll
            for (int rg = 0; rg < 4; ++rg)
#pragma unroll
              for (int cg2 = 0; cg2 < 4; ++cg2) {
                acc[rg][cg2] = __builtin_amdgcn_mfma_f32_16x16x32_bf16(ah[rg], bh[cg2], acc[rg][cg2], 0, 0, 0);
                acc[rg][cg2] = __builtin_amdgcn_mfma_f32_16x16x32_bf16(ah[rg], bl[cg2], acc[rg][cg2], 0, 0, 0);
              }
            __syncthreads();
          }
          int r0 = b * 128;
          int qq = (lane >> 4) << 2;
#pragma unroll
          for (int rg = 0; rg < 4; ++rg) {
#pragma unroll
            for (int cg2 = 0; cg2 < 4; ++cg2) {
              int colg = wc * 64 + cg2 * 16 + frow;
              float bv = bb[colg];
#pragma unroll
              for (int r = 0; r < 4; ++r) {
                int row = r0 + wr * 64 + rg * 16 + qq + r;
                if (row >= NN) continue;
                float val = acc[rg][cg2][r] + bv;
                if (mat == 0)      qbf[(size_t)row * FHH + colg] = f2bf(val * QSCALE);
                else if (mat == 3) xsb[(size_t)row * FHH + colg] = f2bf(val);
                else {
                  int pos = (colg >> 1) * 4 + ((mat == 2) ? 2 : 0) + (colg & 1);
                  kv[(size_t)row * 256 + pos] = f2bf(val);
                }
              }
            }
          }
        }
        __syncthreads();   // LDS reuse safety across grid-stride tiles
      }
    }
    grid.sync();

    // ---------- phase 2: aggregate (4 feat/lane, 2 edges/wave, unroll 8) ----------
    {
      const uint* qb = (const uint*)qbf;
      const uint* xsu = (const uint*)xsb;
      const char* kvb = (const char*)kv;
      int lane = t & 63;
      int hl = lane & 31, half = lane >> 5;
      uint tof = (uint)hl * 16u;
      for (int nb = blockIdx.x; nb < NN / 4; nb += NBLK) {
        int n = nb * 4 + (t >> 6);
        uint2 qp = *reinterpret_cast<const uint2*>(qb + (n << 6) + 2 * hl);
        float qa = bfl(qp.x), qbv = bfh(qp.x), qc = bfl(qp.y), qd = bfh(qp.y);
        int e0 = row_ptr[n], e1 = row_ptr[n + 1];
        float sum = 0.f, a0 = 0.f, a1 = 0.f, a2 = 0.f, a3 = 0.f;
        int i = e0;
#define QKDOT(d, p)                                                  \
        {                                                            \
          p = qa * bfl(d.x);                                         \
          p = fmaf(qbv, bfh(d.x), p);                                \
          p = fmaf(qc, bfl(d.z), p);                                 \
          p = fmaf(qd, bfh(d.z), p);                                 \
        }
        for (; i + 8 <= e1; i += 8) {
          uint oA = colb[i + half] + tof;
          uint oB = colb[i + 2 + half] + tof;
          uint oC = colb[i + 4 + half] + tof;
          uint oD = colb[i + 6 + half] + tof;
          uint4 dA = *(const uint4*)(kvb + oA);
          uint4 dB = *(const uint4*)(kvb + oB);
          uint4 dC = *(const uint4*)(kvb + oC);
          uint4 dD = *(const uint4*)(kvb + oD);
          float pA, pB, pC, pD;
          QKDOT(dA, pA) QKDOT(dB, pB) QKDOT(dC, pC) QKDOT(dD, pD)
          pA += __shfl_xor(pA, 1, 4);  pB += __shfl_xor(pB, 1, 4);
          pC += __shfl_xor(pC, 1, 4);  pD += __shfl_xor(pD, 1, 4);
          pA += __shfl_xor(pA, 2, 4);  pB += __shfl_xor(pB, 2, 4);
          pC += __shfl_xor(pC, 2, 4);  pD += __shfl_xor(pD, 2, 4);
          float wA = exp2f(fminf(pA, 110.f));
          float wB = exp2f(fminf(pB, 110.f));
          float wC = exp2f(fminf(pC, 110.f));
          float wD = exp2f(fminf(pD, 110.f));
          sum += (wA + wB) + (wC + wD);
          a0 = fmaf(wA, bfl(dA.y), fmaf(wB, bfl(dB.y), fmaf(wC, bfl(dC.y), fmaf(wD, bfl(dD.y), a0))));
          a1 = fmaf(wA, bfh(dA.y), fmaf(wB, bfh(dB.y), fmaf(wC, bfh(dC.y), fmaf(wD, bfh(dD.y), a1))));
          a2 = fmaf(wA, bfl(dA.w), fmaf(wB, bfl(dB.w), fmaf(wC, bfl(dC.w), fmaf(wD, bfl(dD.w), a2))));
          a3 = fmaf(wA, bfh(dA.w), fmaf(wB, bfh(dB.w), fmaf(wC, bfh(dC.w), fmaf(wD, bfh(dD.w), a3))));
        }
        for (; i + 2 <= e1; i += 2) {
          uint oA = colb[i + half] + tof;
          uint4 dA = *(const uint4*)(kvb + oA);
          float pA;
          QKDOT(dA, pA)
          pA += __shfl_xor(pA, 1, 4);
          pA += __shfl_xor(pA, 2, 4);
          float wA = exp2f(fminf(pA, 110.f));
          sum += wA;
          a0 = fmaf(wA, bfl(dA.y), a0);
          a1 = fmaf(wA, bfh(dA.y), a1);
          a2 = fmaf(wA, bfl(dA.w), a2);
          a3 = fmaf(wA, bfh(dA.w), a3);
        }
        if (i < e1) {
          uint oA = colb[i] + tof;
          uint4 dA = *(const uint4*)(kvb + oA);
          float pA;
          QKDOT(dA, pA)
          pA += __shfl_xor(pA, 1, 4);
          pA += __shfl_xor(pA, 2, 4);
          float wA = exp2f(fminf(pA, 110.f));
          if (half) wA = 0.f;
          sum += wA;
          a0 = fmaf(wA, bfl(dA.y), a0);
          a1 = fmaf(wA, bfh(dA.y), a1);
          a2 = fmaf(wA, bfl(dA.w), a2);
          a3 = fmaf(wA, bfh(dA.w), a3);
        }
#undef QKDOT
        sum += __shfl_xor(sum, 32);
        a0 += __shfl_xor(a0, 32);
        a1 += __shfl_xor(a1, 32);
        a2 += __shfl_xor(a2, 32);
        a3 += __shfl_xor(a3, 32);
        float inv = 1.f / fmaxf(sum, 1e-16f);
        uint2 xv = *reinterpret_cast<const uint2*>(xsu + (n << 6) + 2 * hl);
        float o0 = fmaf(a0, inv, bfl(xv.x));
        float o1 = fmaf(a1, inv, bfh(xv.x));
        float o2 = fmaf(a2, inv, bfl(xv.y));
        float o3 = fmaf(a3, inv, bfh(xv.y));
        if (half == 0) {
          uint2 o;
          o.x = packbf(o0, o1);
          o.y = packbf(o2, o3);
          *reinterpret_cast<uint2*>(yb + (n << 6) + 2 * hl) = o;
        }
      }
    }
    grid.sync();

    // ---------- phase 3: BN statistics ----------
    {
      float2* s1 = (float2*)sbuf;
      float2* s2 = (float2*)(sbuf + 2048);
      int u = t & 63;
      int grp = t >> 6;
      float2 a = make_float2(0.f, 0.f), b2 = make_float2(0.f, 0.f);
      for (int r = blockIdx.x * 4 + grp; r < NN; r += NBLK * 4) {
        uint d = yb[(size_t)r * 64 + u];
        float x = bfl(d), yv = bfh(d);
        a.x += x; a.y += yv;
        b2.x = fmaf(x, x, b2.x); b2.y = fmaf(yv, yv, b2.y);
      }
      s1[t] = a;
      s2[t] = b2;
      __syncthreads();
      if (grp == 0) {
#pragma unroll
        for (int g = 1; g < 4; ++g) {
          a.x += s1[u + 64 * g].x; a.y += s1[u + 64 * g].y;
          b2.x += s2[u + 64 * g].x; b2.y += s2[u + 64 * g].y;
        }
        atomicAdd(&lstat[2 * u], a.x);
        atomicAdd(&lstat[2 * u + 1], a.y);
        atomicAdd(&lstat[128 + 2 * u], b2.x);
        atomicAdd(&lstat[128 + 2 * u + 1], b2.y);
      }
      __syncthreads();
    }
    grid.sync();

    // ---------- phase 4: post (BN+ReLU -> pool means + Xh fragment write) ----------
    {
      float (*acts)[128] = (float(*)[128])sbuf;
      int* sg = (int*)(sbuf + 4096);
      float* ssc = (float*)(sbuf + 4352);
      float* ssh = (float*)(sbuf + 4864);
      const float* gvec = gamma + (size_t)l * FHH;
      const float* bvec_ = beta + (size_t)l * FHH;
      int write_x = (l + 1 < NL);
      for (int pb = blockIdx.x; pb < 6250; pb += NBLK) {
        if (t < 128) {
          const float invn = 1.f / (float)NN;
          float mu = lstat[t] * invn;
          float var = lstat[128 + t] * invn - mu * mu;
          float sc = gvec[t] * rsqrtf(var + 1e-5f);
          ssc[t] = sc;
          ssh[t] = bvec_[t] - mu * sc;
        }
        if (t < 8) sg[t] = (pb * 8 + t < NN) ? bvec[pb * 8 + t] : -1;
        __syncthreads();
        int row = pb * 8 + (t >> 5);
        int c4 = (t & 31) * 4;
        bool ok = row < NN;
        float4 a = make_float4(0.f, 0.f, 0.f, 0.f);
        if (ok) {
          uint2 u2 = *reinterpret_cast<const uint2*>(yb + (size_t)row * 64 + (c4 >> 1));
          a.x = fmaxf(fmaf(bfl(u2.x), ssc[c4 + 0], ssh[c4 + 0]), 0.f);
          a.y = fmaxf(fmaf(bfh(u2.x), ssc[c4 + 1], ssh[c4 + 1]), 0.f);
          a.z = fmaxf(fmaf(bfl(u2.y), ssc[c4 + 2], ssh[c4 + 2]), 0.f);
          a.w = fmaxf(fmaf(bfh(u2.y), ssc[c4 + 3], ssh[c4 + 3]), 0.f);
        }
        *reinterpret_cast<float4*>(&acts[t >> 5][c4]) = a;
        if (write_x && ok) {
          ushort h0 = f2bf(a.x), h1 = f2bf(a.y), h2 = f2bf(a.z), h3 = f2bf(a.w);
          int bb2 = row >> 7, g = (row & 127) >> 4, frow = row & 15;
          int ks = c4 >> 5, qq = (c4 & 31) >> 3, j = c4 & 7;
          size_t base = ((size_t)ks * NB + bb2) * 4096 + (((g * 4 + qq) * 16) + frow) * 8 + j;
          *reinterpret_cast<uint2*>(Xh + base) =
              make_uint2((uint)h0 | ((uint)h1 << 16), (uint)h2 | ((uint)h3 << 16));
        }
        __syncthreads();
        if (t < 128) {
          float racc = 0.f;
          int cgp = sg[0];
          for (int r = 0; r < 8; ++r) {
            int g = sg[r];
            if (g != cgp) {
              if (cgp >= 0) {
                float p = racc / (float)(gstart[cgp + 1] - gstart[cgp]);
                if (l < 5) atomicAdd(&out[(size_t)cgp * 1024 + l * FHH + t], p);
                else {
                  atomicAdd(&out[(size_t)cgp * 1024 + 5 * FHH + t], p);
                  atomicAdd(&out[(size_t)cgp * 1024 + 6 * FHH + t], p);
                  atomicAdd(&out[(size_t)cgp * 1024 + 7 * FHH + t], p);
                }
              }
              racc = 0.f;
              cgp = g;
            }
            racc += acts[r][t];
          }
          if (cgp >= 0) {
            float p = racc / (float)(gstart[cgp + 1] - gstart[cgp]);
            if (l < 5) atomicAdd(&out[(size_t)cgp * 1024 + l * FHH + t], p);
            else {
              atomicAdd(&out[(size_t)cgp * 1024 + 5 * FHH + t], p);
              atomicAdd(&out[(size_t)cgp * 1024 + 6 * FHH + t], p);
              atomicAdd(&out[(size_t)cgp * 1024 + 7 * FHH + t], p);
            }
          }
        }
        __syncthreads();
      }
    }
    grid.sync();
  }
}

extern "C" void kernel_launch(void* const* d_in, const int* in_sizes, int n_in,
                              void* d_out, int out_size, void* d_ws, size_t ws_size,
                              hipStream_t stream) {
  (void)in_sizes; (void)n_in; (void)ws_size;
  const float* x    = (const float*)d_in[0];
  const int*   ei   = (const int*)d_in[1];
  const int*   bvec = (const int*)d_in[2];
  const float* Wq0  = (const float*)d_in[3];
  const float* bq0  = (const float*)d_in[4];
  const float* Wk0  = (const float*)d_in[5];
  const float* bk0  = (const float*)d_in[6];
  const float* Wv0  = (const float*)d_in[7];
  const float* bv0  = (const float*)d_in[8];
  const float* Ws0  = (const float*)d_in[9];
  const float* bs0  = (const float*)d_in[10];
  const float* WqS  = (const float*)d_in[11];
  const float* bqS  = (const float*)d_in[12];
  const float* WkS  = (const float*)d_in[13];
  const float* bkS  = (const float*)d_in[14];
  const float* WvS  = (const float*)d_in[15];
  const float* bvS  = (const float*)d_in[16];
  const float* WsS  = (const float*)d_in[17];
  const float* bsS  = (const float*)d_in[18];
  const float* gamma = (const float*)d_in[19];
  const float* beta  = (const float*)d_in[20];
  float* out = (float*)d_out;

  char* ws = (char*)d_ws;
  size_t off = 0;
  auto alloc = [&](size_t bytes) {
    void* p = ws + off;
    off = (off + bytes + 255) & ~(size_t)255;
    return p;
  };
  ushort* qbf = (ushort*)alloc((size_t)NN * FHH * 2);
  ushort* xsb = (ushort*)alloc((size_t)NN * FHH * 2);
  uint* yb    = (uint*)alloc((size_t)NN * 64 * 4);
  ushort* kv  = (ushort*)alloc((size_t)NN * 256 * 2);
  ushort* Xh  = (ushort*)alloc((size_t)4 * NB * 4096 * 2 + 8192);
  uint* colb   = (uint*)alloc((size_t)NE * 4);
  int* row_ptr = (int*)alloc((size_t)(NN + 1) * 4);
  int* cursor  = (int*)alloc((size_t)NN * 4);
  int* deg     = (int*)alloc((size_t)NN * 4);
  int* part    = (int*)alloc((size_t)NCH * 4);
  int* gstart  = (int*)alloc((size_t)(NG + 1) * 4);
  float* bstat = (float*)alloc((size_t)NL * 2 * FHH * 4);
  ushort* wsh = (ushort*)alloc((size_t)360448 * 2);
  ushort* wsl = (ushort*)alloc((size_t)360448 * 2);

  const int* srcv = ei;
  const int* dstv = ei + NE;

  hipMemsetAsync(out, 0, (size_t)out_size * 4, stream);
  hipMemsetAsync(deg, 0, (size_t)NN * 4, stream);
  hipMemsetAsync(bstat, 0, (size_t)NL * 2 * FHH * 4, stream);
  k_gstart<<<5, 64, 0, stream>>>(bvec, gstart);
  k_deg<<<(NE + 255) / 256, 256, 0, stream>>>(dstv, deg);
  k_scanA<<<NCH, 256, 0, stream>>>(deg, part);
  k_scanB<<<1, 64, 0, stream>>>(part, row_ptr);
  k_scanC<<<NCH, 1024, 0, stream>>>(deg, part, row_ptr, cursor);
  k_scatter<<<(NE + 255) / 256, 256, 0, stream>>>(srcv, dstv, cursor, colb);
  k_wconv0<<<128, 256, 0, stream>>>(Wq0, Wk0, Wv0, Ws0, wsh, wsl);
  k_wconvS<<<1280, 256, 0, stream>>>(WqS, WkS, WvS, WsS, wsh, wsl);
  k_presplit<64><<<(NN * 16 + 255) / 256, 256, 0, stream>>>(x, Xh);

  // cooperative launch: grid sized to guaranteed co-residency
  int maxB = 0;
  hipOccupancyMaxActiveBlocksPerMultiprocessor(&maxB, k_layers, 256, 0);
  if (maxB < 1) maxB = 1;
  long nblk = (long)maxB * 256;          // 256 CUs on MI355X
  if (nblk > 3136) nblk = 3136;          // 2x gemm tile count; no benefit beyond
  const ushort* wsh_c = wsh;
  const ushort* wsl_c = wsl;
  void* kargs[] = {
    (void*)&wsh_c, (void*)&wsl_c,
    (void*)&bq0, (void*)&bk0, (void*)&bv0, (void*)&bs0,
    (void*)&bqS, (void*)&bkS, (void*)&bvS, (void*)&bsS,
    (void*)&gamma, (void*)&beta,
    (void*)&bvec, (void*)&gstart, (void*)&row_ptr, (void*)&colb,
    (void*)&qbf, (void*)&kv, (void*)&xsb, (void*)&yb, (void*)&Xh,
    (void*)&bstat, (void*)&out
  };
  hipLaunchCooperativeKernel((void*)k_layers, dim3((uint)nblk), dim3(256),
                             kargs, 0, stream);
}

// Round 13
// 910.328 us; speedup vs baseline: 2.7838x; 2.7838x over previous
//
#include <hip/hip_runtime.h>
#include <hip/hip_bf16.h>
#include <math.h>

#define NN 50000
#define NE 800000
#define NG 256
#define FHH 128
#define NL 6
#define NCH 49    // ceil(50000/1024)
#define NB 391    // ceil(50000/128) row-blocks

typedef __attribute__((ext_vector_type(8))) short s16x8;
typedef __attribute__((ext_vector_type(4))) float f32x4;

#define QSCALE 0.36067376022224085f   // 0.25 * log2(e)

__device__ __forceinline__ ushort f2bf(float x) {
  uint u = __float_as_uint(x);
  u += 0x7fffu + ((u >> 16) & 1u);
  return (ushort)(u >> 16);
}
__device__ __forceinline__ float bf2f(ushort h) {
  return __uint_as_float(((uint)h) << 16);
}
__device__ __forceinline__ float bfl(uint u) { return __uint_as_float(u << 16); }
__device__ __forceinline__ float bfh(uint u) { return __uint_as_float(u & 0xffff0000u); }
__device__ __forceinline__ uint packbf(float a, float b) {
  return (uint)f2bf(a) | ((uint)f2bf(b) << 16);
}

__device__ __forceinline__ void gload16(const ushort* g, ushort* l) {
  __builtin_amdgcn_global_load_lds(
      (const __attribute__((address_space(1))) uint*)(const void*)g,
      (__attribute__((address_space(3))) uint*)(void*)l, 16, 0, 0);
}

// ---------------- graph-boundary search (batch_vec sorted) ----------------
__global__ void k_gstart(const int* __restrict__ bv, int* __restrict__ gstart) {
  int g = blockIdx.x * blockDim.x + threadIdx.x;
  if (g > NG) return;
  int lo = 0, hi = NN;
  while (lo < hi) { int mid = (lo + hi) >> 1; if (bv[mid] < g) lo = mid + 1; else hi = mid; }
  gstart[g] = lo;
}

// ---------------- CSR build (by dst) ----------------
__global__ void k_deg(const int* __restrict__ dstv, int* __restrict__ deg) {
  int e = blockIdx.x * blockDim.x + threadIdx.x;
  if (e < NE) atomicAdd(&deg[dstv[e]], 1);
}

__global__ __launch_bounds__(256) void k_scanA(const int* __restrict__ deg, int* __restrict__ part) {
  int b = blockIdx.x, t = threadIdx.x;
  int s = 0;
  for (int j = t; j < 1024; j += 256) { int i = b * 1024 + j; if (i < NN) s += deg[i]; }
  __shared__ int sh[4];
  for (int o = 32; o; o >>= 1) s += __shfl_down(s, o, 64);
  if ((t & 63) == 0) sh[t >> 6] = s;
  __syncthreads();
  if (t == 0) part[b] = sh[0] + sh[1] + sh[2] + sh[3];
}

__global__ void k_scanB(int* __restrict__ part, int* __restrict__ row_ptr) {
  if (threadIdx.x == 0 && blockIdx.x == 0) {
    int run = 0;
    for (int i = 0; i < NCH; ++i) { int v = part[i]; part[i] = run; run += v; }
    row_ptr[NN] = run;
  }
}

__global__ __launch_bounds__(1024) void k_scanC(const int* __restrict__ deg, const int* __restrict__ part,
                                                int* __restrict__ row_ptr, int* __restrict__ cursor) {
  __shared__ int buf[1024];
  int b = blockIdx.x, t = threadIdx.x;
  int i = b * 1024 + t;
  int v = (i < NN) ? deg[i] : 0;
  buf[t] = v;
  __syncthreads();
  for (int off = 1; off < 1024; off <<= 1) {
    int add = (t >= off) ? buf[t - off] : 0;
    __syncthreads();
    buf[t] += add;
    __syncthreads();
  }
  if (i < NN) { int ex = part[b] + buf[t] - v; row_ptr[i] = ex; cursor[i] = ex; }
}

// col stores BYTE offsets of kv rows (src * 512)
__global__ void k_scatter(const int* __restrict__ srcv, const int* __restrict__ dstv,
                          int* __restrict__ cursor, uint* __restrict__ colb) {
  int e = blockIdx.x * blockDim.x + threadIdx.x;
  if (e < NE) {
    int d = dstv[e];
    int pos = atomicAdd(&cursor[d], 1);
    colb[pos] = ((uint)srcv[e]) << 9;
  }
}

// ---------------- weight preconvert: fragment-order tiles ----------------
__device__ __forceinline__ size_t wtile_idx(int k, int c) {
  return (size_t)(k >> 5) * 4096 + ((((c >> 4) * 4 + ((k & 31) >> 3)) * 16 + (c & 15)) * 8 + (k & 7));
}

__global__ __launch_bounds__(256) void k_wconv0(const float* __restrict__ W0, const float* __restrict__ W1,
                                                const float* __restrict__ W2, const float* __restrict__ W3,
                                                ushort* __restrict__ wh, ushort* __restrict__ wl) {
  int id = blockIdx.x * 256 + threadIdx.x;           // 4*64*128 = 32768
  if (id >= 4 * 64 * 128) return;
  int mat = id >> 13, rem = id & 8191;
  int k = rem >> 7, c = rem & 127;
  const float* W = (mat == 0) ? W0 : (mat == 1) ? W1 : (mat == 2) ? W2 : W3;
  float v = W[k * 128 + c];
  ushort h = f2bf(v);
  ushort lo = f2bf(v - bf2f(h));
  size_t dst = (size_t)mat * 8192 + wtile_idx(k, c);
  wh[dst] = h; wl[dst] = lo;
}

__global__ __launch_bounds__(256) void k_wconvS(const float* __restrict__ Wq, const float* __restrict__ Wk,
                                                const float* __restrict__ Wv, const float* __restrict__ Ws,
                                                ushort* __restrict__ wh, ushort* __restrict__ wl) {
  int id = blockIdx.x * 256 + threadIdx.x;           // 5*4*128*128 = 327680
  if (id >= 5 * 4 * 16384) return;
  int lay = id / 65536, rem = id % 65536;
  int mat = rem >> 14, rem2 = rem & 16383;
  int k = rem2 >> 7, c = rem2 & 127;
  const float* W = (mat == 0) ? Wq : (mat == 1) ? Wk : (mat == 2) ? Wv : Ws;
  float v = W[(size_t)lay * 16384 + k * 128 + c];
  ushort h = f2bf(v);
  ushort lo = f2bf(v - bf2f(h));
  size_t dst = 32768 + ((size_t)lay * 4 + mat) * 16384 + wtile_idx(k, c);
  wh[dst] = h; wl[dst] = lo;
}

// ---------------- presplit (layer-0 input only): bf16-high, fragment-order tiled ----------------
template <int K>
__global__ __launch_bounds__(256) void k_presplit(const float* __restrict__ Y,
                                                  ushort* __restrict__ Xh) {
  const int CP = K / 4;
  int idx = blockIdx.x * 256 + threadIdx.x;
  int row = idx / CP;
  int c4 = (idx % CP) * 4;
  if (row >= NN) return;
  float4 v = *reinterpret_cast<const float4*>(Y + (size_t)row * K + c4);
  ushort h0 = f2bf(v.x), h1 = f2bf(v.y), h2 = f2bf(v.z), h3 = f2bf(v.w);
  int b = row >> 7, g = (row & 127) >> 4, frow = row & 15;
  int ks = c4 >> 5, qq = (c4 & 31) >> 3, j = c4 & 7;
  size_t base = ((size_t)ks * NB + b) * 4096 + (((g * 4 + qq) * 16) + frow) * 8 + j;
  *reinterpret_cast<uint2*>(Xh + base) =
      make_uint2((uint)h0 | ((uint)h1 << 16), (uint)h2 | ((uint)h3 << 16));
}

// ---------------- MFMA GEMM (2-pass: ah*bh + ah*bl) ----------------
// Flattened grid with XCD-coherent A-sharing: bids {c, c+8, c+16, c+24} cover the
// 4 mats of one row-block and land on the same XCD -> A L2 hits.
template <int K>
__global__ __launch_bounds__(256, 3) void k_gemm(
    const ushort* __restrict__ Xh,
    const ushort* __restrict__ Wth, const ushort* __restrict__ Wtl,
    const float* __restrict__ b0, const float* __restrict__ b1,
    const float* __restrict__ b2, const float* __restrict__ b3,
    ushort* __restrict__ qbf, ushort* __restrict__ kv, ushort* __restrict__ xsb) {
  __shared__ __align__(16) ushort Ah[4096];
  __shared__ __align__(16) ushort Bh[4096];
  __shared__ __align__(16) ushort Bl[4096];
  int bid = blockIdx.x;
  int mat = (bid >> 3) & 3;
  int b = (bid & 7) + ((bid >> 5) << 3);
  if (b >= NB) return;
  int t = threadIdx.x;
  int lane = t & 63, w = t >> 6;
  int wr = w >> 1, wc = w & 1;
  int frow = lane & 15;
  const ushort* wh = Wth + (size_t)mat * (K * 128);
  const ushort* wl = Wtl + (size_t)mat * (K * 128);
  const float* bb = (mat == 0) ? b0 : (mat == 1) ? b1 : (mat == 2) ? b2 : b3;

  f32x4 acc[4][4];
#pragma unroll
  for (int i = 0; i < 4; ++i)
#pragma unroll
    for (int j = 0; j < 4; ++j)
#pragma unroll
      for (int r = 0; r < 4; ++r) acc[i][j][r] = 0.f;

  int wofs = w * 1024 + lane * 8;
  for (int ks = 0; ks < K / 32; ++ks) {
    size_t abase = ((size_t)ks * NB + b) * 4096;
    const ushort* gAh = Xh + abase + wofs;
    const ushort* gBh = wh + ks * 4096 + wofs;
    const ushort* gBl = wl + ks * 4096 + wofs;
    gload16(gAh, &Ah[w * 1024]);
    gload16(gAh + 512, &Ah[w * 1024 + 512]);
    gload16(gBh, &Bh[w * 1024]);
    gload16(gBh + 512, &Bh[w * 1024 + 512]);
    gload16(gBl, &Bl[w * 1024]);
    gload16(gBl + 512, &Bl[w * 1024 + 512]);
    __syncthreads();
    s16x8 ah[4], bh[4], bl[4];
#pragma unroll
    for (int g = 0; g < 4; ++g) {
      ah[g] = *reinterpret_cast<const s16x8*>(&Ah[(wr * 4 + g) * 512 + lane * 8]);
      bh[g] = *reinterpret_cast<const s16x8*>(&Bh[(wc * 4 + g) * 512 + lane * 8]);
      bl[g] = *reinterpret_cast<const s16x8*>(&Bl[(wc * 4 + g) * 512 + lane * 8]);
    }
#pragma unroll
    for (int rg = 0; rg < 4; ++rg)
#pragma unroll
      for (int cg = 0; cg < 4; ++cg) {
        acc[rg][cg] = __builtin_amdgcn_mfma_f32_16x16x32_bf16(ah[rg], bh[cg], acc[rg][cg], 0, 0, 0);
        acc[rg][cg] = __builtin_amdgcn_mfma_f32_16x16x32_bf16(ah[rg], bl[cg], acc[rg][cg], 0, 0, 0);
      }
    __syncthreads();
  }
  int r0 = b * 128;
  int qq = (lane >> 4) << 2;
#pragma unroll
  for (int rg = 0; rg < 4; ++rg) {
#pragma unroll
    for (int cg = 0; cg < 4; ++cg) {
      int colg = wc * 64 + cg * 16 + frow;
      float bv = bb[colg];
#pragma unroll
      for (int r = 0; r < 4; ++r) {
        int row = r0 + wr * 64 + rg * 16 + qq + r;
        if (row >= NN) continue;
        float val = acc[rg][cg][r] + bv;
        if (mat == 0)      qbf[(size_t)row * FHH + colg] = f2bf(val * QSCALE);
        else if (mat == 3) xsb[(size_t)row * FHH + colg] = f2bf(val);
        else {
          int pos = (colg >> 1) * 4 + ((mat == 2) ? 2 : 0) + (colg & 1);
          kv[(size_t)row * 256 + pos] = f2bf(val);
        }
      }
    }
  }
}

// ---------------- node-centric softmax aggregate ----------------
// 8 features/lane, 16 lanes per edge (quarter-wave), FOUR edges per wave,
// 2-slot unroll = 8 edges in flight. Head = 2-lane group (1 shuffle).
// Cross-quarter combine (2 shuffle rounds) once per node. 4 nodes/block.
__global__ __launch_bounds__(256) void k_agg(const uint* __restrict__ qb,
                                             const ushort* __restrict__ kv,
                                             const uint* __restrict__ xsb,
                                             const int* __restrict__ row_ptr,
                                             const uint* __restrict__ colb,
                                             uint* __restrict__ yb) {
  int n = blockIdx.x * 4 + (threadIdx.x >> 6);
  int lane = threadIdx.x & 63;
  int q_ = lane >> 4, ql = lane & 15;
  uint4 qp = *reinterpret_cast<const uint4*>(qb + (n << 6) + 4 * ql);
  float q0 = bfl(qp.x), q1 = bfh(qp.x), q2 = bfl(qp.y), q3 = bfh(qp.y);
  float q4 = bfl(qp.z), q5 = bfh(qp.z), q6 = bfl(qp.w), q7 = bfh(qp.w);
  const char* kvb = (const char*)kv;
  uint tof = (uint)ql * 32u;
  int e0 = row_ptr[n], e1 = row_ptr[n + 1];
  float sum = 0.f;
  float a0 = 0.f, a1 = 0.f, a2 = 0.f, a3 = 0.f;
  float a4 = 0.f, a5 = 0.f, a6 = 0.f, a7 = 0.f;
  int i = e0;
// d0,d1 = two uint4 (32B) of one kv row: {k01,v01,k23,v23 | k45,v45,k67,v67}
#define EDOT(d0, d1, p)                         \
  {                                             \
    p = q0 * bfl(d0.x);                         \
    p = fmaf(q1, bfh(d0.x), p);                 \
    p = fmaf(q2, bfl(d0.z), p);                 \
    p = fmaf(q3, bfh(d0.z), p);                 \
    p = fmaf(q4, bfl(d1.x), p);                 \
    p = fmaf(q5, bfh(d1.x), p);                 \
    p = fmaf(q6, bfl(d1.z), p);                 \
    p = fmaf(q7, bfh(d1.z), p);                 \
  }
#define EACC(d0, d1, wv)                        \
  {                                             \
    a0 = fmaf(wv, bfl(d0.y), a0);               \
    a1 = fmaf(wv, bfh(d0.y), a1);               \
    a2 = fmaf(wv, bfl(d0.w), a2);               \
    a3 = fmaf(wv, bfh(d0.w), a3);               \
    a4 = fmaf(wv, bfl(d1.y), a4);               \
    a5 = fmaf(wv, bfh(d1.y), a5);               \
    a6 = fmaf(wv, bfl(d1.w), a6);               \
    a7 = fmaf(wv, bfh(d1.w), a7);               \
  }
  for (; i + 8 <= e1; i += 8) {
    uint oA = colb[i + q_] + tof;
    uint oB = colb[i + 4 + q_] + tof;
    uint4 dA0 = *(const uint4*)(kvb + oA);
    uint4 dA1 = *(const uint4*)(kvb + oA + 16);
    uint4 dB0 = *(const uint4*)(kvb + oB);
    uint4 dB1 = *(const uint4*)(kvb + oB + 16);
    float pA, pB;
    EDOT(dA0, dA1, pA)
    EDOT(dB0, dB1, pB)
    pA += __shfl_xor(pA, 1, 2);
    pB += __shfl_xor(pB, 1, 2);
    float wA = exp2f(fminf(pA, 110.f));
    float wB = exp2f(fminf(pB, 110.f));
    sum += wA + wB;
    EACC(dA0, dA1, wA)
    EACC(dB0, dB1, wB)
  }
  if (i + 4 <= e1) {
    uint oA = colb[i + q_] + tof;
    uint4 dA0 = *(const uint4*)(kvb + oA);
    uint4 dA1 = *(const uint4*)(kvb + oA + 16);
    float pA;
    EDOT(dA0, dA1, pA)
    pA += __shfl_xor(pA, 1, 2);
    float wA = exp2f(fminf(pA, 110.f));
    sum += wA;
    EACC(dA0, dA1, wA)
    i += 4;
  }
  if (i < e1) {
    int idx = i + q_;
    bool valid = idx < e1;
    uint oA = colb[valid ? idx : e0] + tof;
    uint4 dA0 = *(const uint4*)(kvb + oA);
    uint4 dA1 = *(const uint4*)(kvb + oA + 16);
    float pA;
    EDOT(dA0, dA1, pA)
    pA += __shfl_xor(pA, 1, 2);
    float wA = exp2f(fminf(pA, 110.f));
    if (!valid) wA = 0.f;
    sum += wA;
    EACC(dA0, dA1, wA)
  }
#undef EDOT
#undef EACC
  // combine quarters (each held a disjoint subset of edges)
  sum += __shfl_xor(sum, 16);  sum += __shfl_xor(sum, 32);
  a0 += __shfl_xor(a0, 16);    a0 += __shfl_xor(a0, 32);
  a1 += __shfl_xor(a1, 16);    a1 += __shfl_xor(a1, 32);
  a2 += __shfl_xor(a2, 16);    a2 += __shfl_xor(a2, 32);
  a3 += __shfl_xor(a3, 16);    a3 += __shfl_xor(a3, 32);
  a4 += __shfl_xor(a4, 16);    a4 += __shfl_xor(a4, 32);
  a5 += __shfl_xor(a5, 16);    a5 += __shfl_xor(a5, 32);
  a6 += __shfl_xor(a6, 16);    a6 += __shfl_xor(a6, 32);
  a7 += __shfl_xor(a7, 16);    a7 += __shfl_xor(a7, 32);
  if (q_ == 0) {
    float inv = 1.f / fmaxf(sum, 1e-16f);
    uint4 xv = *reinterpret_cast<const uint4*>(xsb + (n << 6) + 4 * ql);
    uint4 o;
    o.x = packbf(fmaf(a0, inv, bfl(xv.x)), fmaf(a1, inv, bfh(xv.x)));
    o.y = packbf(fmaf(a2, inv, bfl(xv.y)), fmaf(a3, inv, bfh(xv.y)));
    o.z = packbf(fmaf(a4, inv, bfl(xv.z)), fmaf(a5, inv, bfh(xv.z)));
    o.w = packbf(fmaf(a6, inv, bfl(xv.w)), fmaf(a7, inv, bfh(xv.w)));
    *reinterpret_cast<uint4*>(yb + (n << 6) + 4 * ql) = o;
  }
}

// ---------------- BN statistics (packed bf16 y) ----------------
__global__ __launch_bounds__(256) void k_bnstats(const uint* __restrict__ yb,
                                                 float* __restrict__ stats) {
  __shared__ float2 s1[256], s2[256];
  int u = threadIdx.x & 63;
  int grp = threadIdx.x >> 6;
  float2 a = make_float2(0.f, 0.f), b = make_float2(0.f, 0.f);
  for (int r = blockIdx.x * 4 + grp; r < NN; r += 1024) {
    uint d = yb[(size_t)r * 64 + u];
    float x = bfl(d), yv = bfh(d);
    a.x += x; a.y += yv;
    b.x = fmaf(x, x, b.x); b.y = fmaf(yv, yv, b.y);
  }
  s1[threadIdx.x] = a;
  s2[threadIdx.x] = b;
  __syncthreads();
  if (grp == 0) {
#pragma unroll
    for (int g = 1; g < 4; ++g) {
      a.x += s1[u + 64 * g].x; a.y += s1[u + 64 * g].y;
      b.x += s2[u + 64 * g].x; b.y += s2[u + 64 * g].y;
    }
    atomicAdd(&stats[2 * u], a.x);
    atomicAdd(&stats[2 * u + 1], a.y);
    atomicAdd(&stats[128 + 2 * u], b.x);
    atomicAdd(&stats[128 + 2 * u + 1], b.y);
  }
}

// ---------------- fused post: BN+ReLU once -> (pool atomic means) + (bf16-high fragment write) ----
template <int WRITE_X>
__global__ __launch_bounds__(256) void k_post(const uint* __restrict__ yb,
                                              const float* __restrict__ st,
                                              const float* __restrict__ gvec,
                                              const float* __restrict__ bvec_,
                                              const int* __restrict__ bv,
                                              const int* __restrict__ gstart,
                                              float* __restrict__ out, int layer,
                                              ushort* __restrict__ Xh) {
  __shared__ float acts[8][128];
  __shared__ int sg[8];
  __shared__ float ssc[128], ssh[128];
  int b = blockIdx.x, t = threadIdx.x;
  if (t < 128) {
    const float invn = 1.f / (float)NN;
    float mu = st[t] * invn;
    float var = st[128 + t] * invn - mu * mu;
    float sc = gvec[t] * rsqrtf(var + 1e-5f);
    ssc[t] = sc;
    ssh[t] = bvec_[t] - mu * sc;
  }
  if (t < 8) sg[t] = (b * 8 + t < NN) ? bv[b * 8 + t] : -1;
  __syncthreads();
  int row = b * 8 + (t >> 5);
  int c4 = (t & 31) * 4;
  bool ok = row < NN;
  float4 a = make_float4(0.f, 0.f, 0.f, 0.f);
  if (ok) {
    uint2 u2 = *reinterpret_cast<const uint2*>(yb + (size_t)row * 64 + (c4 >> 1));
    a.x = fmaxf(fmaf(bfl(u2.x), ssc[c4 + 0], ssh[c4 + 0]), 0.f);
    a.y = fmaxf(fmaf(bfh(u2.x), ssc[c4 + 1], ssh[c4 + 1]), 0.f);
    a.z = fmaxf(fmaf(bfl(u2.y), ssc[c4 + 2], ssh[c4 + 2]), 0.f);
    a.w = fmaxf(fmaf(bfh(u2.y), ssc[c4 + 3], ssh[c4 + 3]), 0.f);
  }
  *reinterpret_cast<float4*>(&acts[t >> 5][c4]) = a;
  if (WRITE_X && ok) {
    ushort h0 = f2bf(a.x), h1 = f2bf(a.y), h2 = f2bf(a.z), h3 = f2bf(a.w);
    int bb = row >> 7, g = (row & 127) >> 4, frow = row & 15;
    int ks = c4 >> 5, qq = (c4 & 31) >> 3, j = c4 & 7;
    size_t base = ((size_t)ks * NB + bb) * 4096 + (((g * 4 + qq) * 16) + frow) * 8 + j;
    *reinterpret_cast<uint2*>(Xh + base) =
        make_uint2((uint)h0 | ((uint)h1 << 16), (uint)h2 | ((uint)h3 << 16));
  }
  __syncthreads();
  if (t < 128) {
    float racc = 0.f;
    int cg = sg[0];
    for (int r = 0; r < 8; ++r) {
      int g = sg[r];
      if (g != cg) {
        if (cg >= 0) {
          float p = racc / (float)(gstart[cg + 1] - gstart[cg]);
          if (layer < 5) atomicAdd(&out[(size_t)cg * 1024 + layer * FHH + t], p);
          else {
            atomicAdd(&out[(size_t)cg * 1024 + 5 * FHH + t], p);
            atomicAdd(&out[(size_t)cg * 1024 + 6 * FHH + t], p);
            atomicAdd(&out[(size_t)cg * 1024 + 7 * FHH + t], p);
          }
        }
        racc = 0.f;
        cg = g;
      }
      racc += acts[r][t];
    }
    if (cg >= 0) {
      float p = racc / (float)(gstart[cg + 1] - gstart[cg]);
      if (layer < 5) atomicAdd(&out[(size_t)cg * 1024 + layer * FHH + t], p);
      else {
        atomicAdd(&out[(size_t)cg * 1024 + 5 * FHH + t], p);
        atomicAdd(&out[(size_t)cg * 1024 + 6 * FHH + t], p);
        atomicAdd(&out[(size_t)cg * 1024 + 7 * FHH + t], p);
      }
    }
  }
}

extern "C" void kernel_launch(void* const* d_in, const int* in_sizes, int n_in,
                              void* d_out, int out_size, void* d_ws, size_t ws_size,
                              hipStream_t stream) {
  (void)in_sizes; (void)n_in; (void)ws_size;
  const float* x    = (const float*)d_in[0];
  const int*   ei   = (const int*)d_in[1];
  const int*   bvec = (const int*)d_in[2];
  const float* Wq0  = (const float*)d_in[3];
  const float* bq0  = (const float*)d_in[4];
  const float* Wk0  = (const float*)d_in[5];
  const float* bk0  = (const float*)d_in[6];
  const float* Wv0  = (const float*)d_in[7];
  const float* bv0  = (const float*)d_in[8];
  const float* Ws0  = (const float*)d_in[9];
  const float* bs0  = (const float*)d_in[10];
  const float* WqS  = (const float*)d_in[11];
  const float* bqS  = (const float*)d_in[12];
  const float* WkS  = (const float*)d_in[13];
  const float* bkS  = (const float*)d_in[14];
  const float* WvS  = (const float*)d_in[15];
  const float* bvS  = (const float*)d_in[16];
  const float* WsS  = (const float*)d_in[17];
  const float* bsS  = (const float*)d_in[18];
  const float* gamma = (const float*)d_in[19];
  const float* beta  = (const float*)d_in[20];
  float* out = (float*)d_out;

  char* ws = (char*)d_ws;
  size_t off = 0;
  auto alloc = [&](size_t bytes) {
    void* p = ws + off;
    off = (off + bytes + 255) & ~(size_t)255;
    return p;
  };
  ushort* qbf = (ushort*)alloc((size_t)NN * FHH * 2);
  ushort* xsb = (ushort*)alloc((size_t)NN * FHH * 2);
  uint* yb    = (uint*)alloc((size_t)NN * 64 * 4);
  ushort* kv  = (ushort*)alloc((size_t)NN * 256 * 2);
  ushort* Xh  = (ushort*)alloc((size_t)4 * NB * 4096 * 2 + 8192);
  uint* colb   = (uint*)alloc((size_t)NE * 4);
  int* row_ptr = (int*)alloc((size_t)(NN + 1) * 4);
  int* cursor  = (int*)alloc((size_t)NN * 4);
  int* deg     = (int*)alloc((size_t)NN * 4);
  int* part    = (int*)alloc((size_t)NCH * 4);
  int* gstart  = (int*)alloc((size_t)(NG + 1) * 4);
  float* bstat = (float*)alloc((size_t)NL * 2 * FHH * 4);   // [layer][{sum,sumsq}][128]
  ushort* wsh = (ushort*)alloc((size_t)360448 * 2);
  ushort* wsl = (ushort*)alloc((size_t)360448 * 2);

  const int* srcv = ei;
  const int* dstv = ei + NE;

  hipMemsetAsync(out, 0, (size_t)out_size * 4, stream);
  hipMemsetAsync(deg, 0, (size_t)NN * 4, stream);
  hipMemsetAsync(bstat, 0, (size_t)NL * 2 * FHH * 4, stream);
  k_gstart<<<5, 64, 0, stream>>>(bvec, gstart);
  k_deg<<<(NE + 255) / 256, 256, 0, stream>>>(dstv, deg);
  k_scanA<<<NCH, 256, 0, stream>>>(deg, part);
  k_scanB<<<1, 64, 0, stream>>>(part, row_ptr);
  k_scanC<<<NCH, 1024, 0, stream>>>(deg, part, row_ptr, cursor);
  k_scatter<<<(NE + 255) / 256, 256, 0, stream>>>(srcv, dstv, cursor, colb);
  k_wconv0<<<128, 256, 0, stream>>>(Wq0, Wk0, Wv0, Ws0, wsh, wsl);
  k_wconvS<<<1280, 256, 0, stream>>>(WqS, WkS, WvS, WsS, wsh, wsl);
  k_presplit<64><<<(NN * 16 + 255) / 256, 256, 0, stream>>>(x, Xh);

  const int GEMM_GRID = 49 * 32;   // ceil(NB/8)*32 : 4 mats x NB blocks, XCD-swizzled
  for (int l = 0; l < NL; ++l) {
    const ushort* WthL = wsh + ((l == 0) ? 0 : (size_t)32768 + (size_t)(l - 1) * 65536);
    const ushort* WtlL = wsl + ((l == 0) ? 0 : (size_t)32768 + (size_t)(l - 1) * 65536);
    const float *bq_, *bk_, *bv_, *bs_;
    if (l == 0) { bq_ = bq0; bk_ = bk0; bv_ = bv0; bs_ = bs0; }
    else {
      size_t bo = (size_t)(l - 1) * FHH;
      bq_ = bqS + bo; bk_ = bkS + bo; bv_ = bvS + bo; bs_ = bsS + bo;
    }
    if (l == 0)
      k_gemm<64><<<GEMM_GRID, 256, 0, stream>>>(Xh, WthL, WtlL, bq_, bk_, bv_, bs_, qbf, kv, xsb);
    else
      k_gemm<128><<<GEMM_GRID, 256, 0, stream>>>(Xh, WthL, WtlL, bq_, bk_, bv_, bs_, qbf, kv, xsb);
    k_agg<<<NN / 4, 256, 0, stream>>>((const uint*)qbf, kv, (const uint*)xsb, row_ptr, colb, yb);
    float* lstat = bstat + (size_t)l * 2 * FHH;
    k_bnstats<<<256, 256, 0, stream>>>(yb, lstat);
    if (l + 1 < NL)
      k_post<1><<<6250, 256, 0, stream>>>(yb, lstat, gamma + (size_t)l * FHH,
                                          beta + (size_t)l * FHH, bvec, gstart, out, l, Xh);
    else
      k_post<0><<<6250, 256, 0, stream>>>(yb, lstat, gamma + (size_t)l * FHH,
                                          beta + (size_t)l * FHH, bvec, gstart, out, l, Xh);
  }
}